// Round 16
// baseline (238.674 us; speedup 1.0000x reference)
//
#include <hip/hip_runtime.h>
#include <math.h>

typedef unsigned int u32;

constexpr int NN = 100000;   // nodes
constexpr int NE = 3200000;  // edges
constexpr int DF = 512;      // in features
constexpr int NH = 16;       // hidden
constexpr int NC = 40;       // classes

constexpr int NB  = 512;     // buckets
constexpr int BSZ = 196;     // nodes per bucket (512*196 >= NN)
constexpr int CAP = 7168;    // per-bucket edge capacity (mean 6250, +11 sigma)
constexpr int SCHUNK = 8192;
constexpr int SGRID  = (NE + SCHUNK - 1) / SCHUNK;  // 391 blocks

// ---------------------------------------------------------------- bf16 helpers
__device__ __forceinline__ u32 pack_bf2(float lo, float hi) {
    u32 a = __float_as_uint(lo), b = __float_as_uint(hi);
    a += 0x7FFFu + ((a >> 16) & 1u);   // RNE
    b += 0x7FFFu + ((b >> 16) & 1u);
    return (a >> 16) | (b & 0xFFFF0000u);
}
__device__ __forceinline__ float bf_lo(u32 u) { return __uint_as_float(u << 16); }
__device__ __forceinline__ float bf_hi(u32 u) { return __uint_as_float(u & 0xFFFF0000u); }

// ---------------------------------------------------------------- init bucket cursors
__global__ void k_init(int* __restrict__ gcur) {
    int i = blockIdx.x * blockDim.x + threadIdx.x;
    if (i < NB) gcur[i] = i * CAP;
}

// ---------------------------------------------------------------- bucket counting-scatter
// Block-local counting sort by bucket, then COALESCED write-out (R15 proven).
__global__ __launch_bounds__(1024) void k_scatter_bucket(
    const int* __restrict__ src, const int* __restrict__ dst,
    int* __restrict__ gcur, u32* __restrict__ pairs) {
    __shared__ int hist[NB];
    __shared__ int lofs[NB];
    __shared__ int gpos[NB];
    __shared__ int lcur[NB];
    __shared__ u32 buf[SCHUNK];   // 32 KB
    const int t = threadIdx.x;
    for (int i = t; i < NB; i += 1024) { hist[i] = 0; lcur[i] = 0; }
    __syncthreads();

    const int base  = blockIdx.x * SCHUNK;
    const int total = min(SCHUNK, NE - base);
    int dr[SCHUNK / 1024], sr[SCHUNK / 1024];
    #pragma unroll
    for (int k = 0; k < SCHUNK / 1024; ++k) {
        const int i = base + k * 1024 + t;
        if (i < NE) {
            dr[k] = dst[i];
            sr[k] = src[i];
            atomicAdd(&hist[(unsigned)dr[k] / BSZ], 1);
        }
    }
    __syncthreads();
    if (t < NB) {
        lofs[t] = hist[t];
        if (hist[t]) gpos[t] = atomicAdd(&gcur[t], hist[t]);
    }
    __syncthreads();
    #pragma unroll
    for (int off = 1; off < NB; off <<= 1) {
        int v = 0;
        if (t < NB && t >= off) v = lofs[t - off];
        __syncthreads();
        if (t < NB) lofs[t] += v;
        __syncthreads();
    }
    if (t < NB) lofs[t] -= hist[t];   // exclusive
    __syncthreads();
    #pragma unroll
    for (int k = 0; k < SCHUNK / 1024; ++k) {
        const int i = base + k * 1024 + t;
        if (i < NE) {
            const unsigned d  = (unsigned)dr[k];
            const unsigned b  = d / BSZ;
            const unsigned dl = d - b * BSZ;
            const int off = atomicAdd(&lcur[b], 1);
            buf[lofs[b] + off] = (unsigned)sr[k] | (dl << 17);
        }
    }
    __syncthreads();
    for (int i = t; i < total; i += 1024) {
        int lo = 0, hi = NB - 1;
        #pragma unroll
        for (int s = 0; s < 9; ++s) {
            const int mid = (lo + hi + 1) >> 1;
            if (lofs[mid] <= i) lo = mid; else hi = mid - 1;
        }
        pairs[gpos[lo] + (i - lofs[lo])] = buf[i];
    }
}

// ---------------------------------------------------------------- per-bucket counting sort by dl
__global__ __launch_bounds__(1024) void k_sort_bucket(
    const u32* __restrict__ pairs, const int* __restrict__ gcur,
    int* __restrict__ esrc_s, int* __restrict__ row_start,
    int* __restrict__ degs, float* __restrict__ dinv) {
    __shared__ int hist[BSZ];
    __shared__ int scan[256];
    __shared__ int cur[BSZ];
    const int b = blockIdx.x, t = threadIdx.x;
    if (t < BSZ) hist[t] = 0;
    __syncthreads();

    const int base = b * CAP;
    const int end  = gcur[b];
    for (int p = base + t; p < end; p += 1024)
        atomicAdd(&hist[pairs[p] >> 17], 1);
    __syncthreads();

    const int h = (t < BSZ) ? hist[t] : 0;
    if (t < 256) scan[t] = (t < BSZ) ? h : 0;
    __syncthreads();
    #pragma unroll
    for (int off = 1; off < 256; off <<= 1) {
        int u = 0;
        if (t < 256 && t >= off) u = scan[t - off];
        __syncthreads();
        if (t < 256) scan[t] += u;
        __syncthreads();
    }
    if (t < BSZ) {
        const int st = scan[t] - h;   // exclusive
        cur[t] = st;
        const int n = b * BSZ + t;
        if (n < NN) {
            row_start[n] = base + st;
            degs[n] = h;
            dinv[n] = rsqrtf((float)(h + 1));
        }
    }
    __syncthreads();
    for (int p = base + t; p < end; p += 1024) {
        const u32 u = pairs[p];
        const int dl = u >> 17;
        const int pos = atomicAdd(&cur[dl], 1);
        esrc_s[base + pos] = (int)(u & 0x1FFFFu);
    }
}

// ---------------------------------------------------------------- layer-1 GEMM (R10 proven)
__global__ __launch_bounds__(256) void k_gemm1(
    const float* __restrict__ x, const float* __restrict__ W1,
    const float* __restrict__ dinv, u32* __restrict__ h1b) {
    __shared__ __align__(16) float sX[64 * 68];   // 17.4 KB
    __shared__ __align__(16) float sW[64 * 16];   // 4 KB
    const int t    = threadIdx.x;
    const int lane = t & 63;
    const int og   = t >> 6;

    const int row0 = blockIdx.x * 64;
    const int lr = t >> 2, cq = t & 3;
    const bool rv = (row0 + lr) < NN;
    const float* xrow = x + (size_t)(row0 + lr) * DF + cq * 16;

    float4 pf[4];
    #pragma unroll
    for (int j = 0; j < 4; ++j)
        pf[j] = rv ? *(const float4*)&xrow[4 * j] : make_float4(0.f, 0.f, 0.f, 0.f);
    float4 wpf = *(const float4*)&W1[t * 4];

    float a0 = 0.f, a1 = 0.f, a2 = 0.f, a3 = 0.f;

    for (int kc = 0; kc < DF; kc += 64) {
        #pragma unroll
        for (int j = 0; j < 4; ++j)
            *(float4*)&sX[lr * 68 + cq * 16 + 4 * j] = pf[j];
        *(float4*)&sW[t * 4] = wpf;
        __syncthreads();
        if (kc + 64 < DF) {
            #pragma unroll
            for (int j = 0; j < 4; ++j)
                pf[j] = rv ? *(const float4*)&xrow[kc + 64 + 4 * j]
                           : make_float4(0.f, 0.f, 0.f, 0.f);
            wpf = *(const float4*)&W1[(kc + 64) * NH + t * 4];
        }
        #pragma unroll
        for (int g = 0; g < 16; ++g) {
            const float4 xv4 = *(const float4*)&sX[lane * 68 + g * 4];
            const float xa[4] = {xv4.x, xv4.y, xv4.z, xv4.w};
            #pragma unroll
            for (int j = 0; j < 4; ++j) {
                const float4 wv = *(const float4*)&sW[(g * 4 + j) * NH + og * 4];
                a0 = fmaf(xa[j], wv.x, a0);
                a1 = fmaf(xa[j], wv.y, a1);
                a2 = fmaf(xa[j], wv.z, a2);
                a3 = fmaf(xa[j], wv.w, a3);
            }
        }
        __syncthreads();
    }
    const int gr = row0 + lane;
    if (gr < NN) {
        const float s = dinv[gr];
        const u32 w0 = pack_bf2(a0 * s, a1 * s);
        const u32 w1 = pack_bf2(a2 * s, a3 * s);
        *(uint2*)&h1b[(size_t)gr * 8 + og * 2] = make_uint2(w0, w1);
    }
}

// ---------------------------------------------------------------- CSR gather agg, layer 1
// wave per node: lane = h (row half 0..1, uint4) + 2*g (edge group 0..31)
// 32 edges in flight per wave (4x MLP vs 8-group version).
__global__ __launch_bounds__(1024) void k_agg1(
    const int* __restrict__ row_start, const int* __restrict__ degs,
    const int* __restrict__ esrc_s, const u32* __restrict__ h1b,
    const float* __restrict__ dinv, const float* __restrict__ b1,
    u32* __restrict__ A1) {
    const int node = blockIdx.x * 16 + (threadIdx.x >> 6);
    if (node >= NN) return;
    const int lane = threadIdx.x & 63;
    const int h = lane & 1;
    const int g = lane >> 1;
    const int beg = row_start[node];
    const int end = beg + degs[node];

    float s0 = 0.f, s1 = 0.f, s2 = 0.f, s3 = 0.f;
    float s4 = 0.f, s5 = 0.f, s6 = 0.f, s7 = 0.f;
    for (int e = beg + g; e < end; e += 32) {
        const int s = esrc_s[e];
        const uint4 u = *(const uint4*)&h1b[(size_t)s * 8 + h * 4];
        s0 += bf_lo(u.x); s1 += bf_hi(u.x);
        s2 += bf_lo(u.y); s3 += bf_hi(u.y);
        s4 += bf_lo(u.z); s5 += bf_hi(u.z);
        s6 += bf_lo(u.w); s7 += bf_hi(u.w);
    }
    #pragma unroll
    for (int off = 2; off < 64; off <<= 1) {
        s0 += __shfl_xor(s0, off); s1 += __shfl_xor(s1, off);
        s2 += __shfl_xor(s2, off); s3 += __shfl_xor(s3, off);
        s4 += __shfl_xor(s4, off); s5 += __shfl_xor(s5, off);
        s6 += __shfl_xor(s6, off); s7 += __shfl_xor(s7, off);
    }

    if (g == 0) {   // lanes 0 (ch 0..7), 1 (ch 8..15)
        const float dn = dinv[node];
        const uint4 su = *(const uint4*)&h1b[(size_t)node * 8 + h * 4];
        const float p0 = (s0 + bf_lo(su.x)) * dn + b1[8 * h + 0];
        const float p1 = (s1 + bf_hi(su.x)) * dn + b1[8 * h + 1];
        const float p2 = (s2 + bf_lo(su.y)) * dn + b1[8 * h + 2];
        const float p3 = (s3 + bf_hi(su.y)) * dn + b1[8 * h + 3];
        const float p4 = (s4 + bf_lo(su.z)) * dn + b1[8 * h + 4];
        const float p5 = (s5 + bf_hi(su.z)) * dn + b1[8 * h + 5];
        const float p6 = (s6 + bf_lo(su.w)) * dn + b1[8 * h + 6];
        const float p7 = (s7 + bf_hi(su.w)) * dn + b1[8 * h + 7];
        uint4 o;
        o.x = pack_bf2(fmaxf(p0, 0.f) * dn, fmaxf(p1, 0.f) * dn);
        o.y = pack_bf2(fmaxf(p2, 0.f) * dn, fmaxf(p3, 0.f) * dn);
        o.z = pack_bf2(fmaxf(p4, 0.f) * dn, fmaxf(p5, 0.f) * dn);
        o.w = pack_bf2(fmaxf(p6, 0.f) * dn, fmaxf(p7, 0.f) * dn);
        *(uint4*)&A1[(size_t)node * 8 + h * 4] = o;
    }
}

// ---------------------------------------------------------------- CSR gather agg, layer 2 + W2 + log_softmax
__global__ __launch_bounds__(1024) void k_agg2_final(
    const int* __restrict__ row_start, const int* __restrict__ degs,
    const int* __restrict__ esrc_s, const u32* __restrict__ A1,
    const float* __restrict__ dinv, const float* __restrict__ W2,
    const float* __restrict__ b2, float* __restrict__ out) {
    __shared__ float sW2[NH * NC];
    __shared__ float sb2[NC];
    const int t = threadIdx.x;
    if (t < NH * NC) sW2[t] = W2[t];
    if (t >= 1024 - NC) sb2[t - (1024 - NC)] = b2[t - (1024 - NC)];
    __syncthreads();

    const int node = blockIdx.x * 16 + (t >> 6);
    if (node >= NN) return;
    const int lane = t & 63;
    const int h = lane & 1;
    const int g = lane >> 1;
    const int beg = row_start[node];
    const int end = beg + degs[node];

    float s0 = 0.f, s1 = 0.f, s2 = 0.f, s3 = 0.f;
    float s4 = 0.f, s5 = 0.f, s6 = 0.f, s7 = 0.f;
    for (int e = beg + g; e < end; e += 32) {
        const int s = esrc_s[e];
        const uint4 u = *(const uint4*)&A1[(size_t)s * 8 + h * 4];
        s0 += bf_lo(u.x); s1 += bf_hi(u.x);
        s2 += bf_lo(u.y); s3 += bf_hi(u.y);
        s4 += bf_lo(u.z); s5 += bf_hi(u.z);
        s6 += bf_lo(u.w); s7 += bf_hi(u.w);
    }
    #pragma unroll
    for (int off = 2; off < 64; off <<= 1) {
        s0 += __shfl_xor(s0, off); s1 += __shfl_xor(s1, off);
        s2 += __shfl_xor(s2, off); s3 += __shfl_xor(s3, off);
        s4 += __shfl_xor(s4, off); s5 += __shfl_xor(s5, off);
        s6 += __shfl_xor(s6, off); s7 += __shfl_xor(s7, off);
    }

    // lane parity h: channels 8h..8h+7
    const float dn = dinv[node];
    const uint4 su = *(const uint4*)&A1[(size_t)node * 8 + h * 4];
    const float g0 = (s0 + bf_lo(su.x)) * dn;
    const float g1 = (s1 + bf_hi(su.x)) * dn;
    const float g2 = (s2 + bf_lo(su.y)) * dn;
    const float g3 = (s3 + bf_hi(su.y)) * dn;
    const float g4 = (s4 + bf_lo(su.z)) * dn;
    const float g5 = (s5 + bf_hi(su.z)) * dn;
    const float g6 = (s6 + bf_lo(su.w)) * dn;
    const float g7 = (s7 + bf_hi(su.w)) * dn;

    float z = (lane < NC) ? sb2[lane] : -1e30f;
    const bool act = (lane < NC);
    {   // ch j from lane 0, ch 8+j from lane 1
        float v0, v1;
        v0 = __shfl(g0, 0); v1 = __shfl(g0, 1);
        if (act) { z = fmaf(v0, sW2[0 * NC + lane], z); z = fmaf(v1, sW2[8 * NC + lane], z); }
        v0 = __shfl(g1, 0); v1 = __shfl(g1, 1);
        if (act) { z = fmaf(v0, sW2[1 * NC + lane], z); z = fmaf(v1, sW2[9 * NC + lane], z); }
        v0 = __shfl(g2, 0); v1 = __shfl(g2, 1);
        if (act) { z = fmaf(v0, sW2[2 * NC + lane], z); z = fmaf(v1, sW2[10 * NC + lane], z); }
        v0 = __shfl(g3, 0); v1 = __shfl(g3, 1);
        if (act) { z = fmaf(v0, sW2[3 * NC + lane], z); z = fmaf(v1, sW2[11 * NC + lane], z); }
        v0 = __shfl(g4, 0); v1 = __shfl(g4, 1);
        if (act) { z = fmaf(v0, sW2[4 * NC + lane], z); z = fmaf(v1, sW2[12 * NC + lane], z); }
        v0 = __shfl(g5, 0); v1 = __shfl(g5, 1);
        if (act) { z = fmaf(v0, sW2[5 * NC + lane], z); z = fmaf(v1, sW2[13 * NC + lane], z); }
        v0 = __shfl(g6, 0); v1 = __shfl(g6, 1);
        if (act) { z = fmaf(v0, sW2[6 * NC + lane], z); z = fmaf(v1, sW2[14 * NC + lane], z); }
        v0 = __shfl(g7, 0); v1 = __shfl(g7, 1);
        if (act) { z = fmaf(v0, sW2[7 * NC + lane], z); z = fmaf(v1, sW2[15 * NC + lane], z); }
    }
    float m = z;
    #pragma unroll
    for (int off = 1; off < 64; off <<= 1) m = fmaxf(m, __shfl_xor(m, off));
    float sum = act ? __expf(z - m) : 0.f;
    #pragma unroll
    for (int off = 1; off < 64; off <<= 1) sum += __shfl_xor(sum, off);
    const float lse = m + __logf(sum);
    if (act) out[(size_t)node * NC + lane] = z - lse;
}

// ---------------------------------------------------------------- launch
extern "C" void kernel_launch(void* const* d_in, const int* in_sizes, int n_in,
                              void* d_out, int out_size, void* d_ws, size_t ws_size,
                              hipStream_t stream) {
    const float* x  = (const float*)d_in[0];
    const int*   ei = (const int*)d_in[1];   // [2, NE] flat int32
    const float* W1 = (const float*)d_in[2];
    const float* b1 = (const float*)d_in[3];
    const float* W2 = (const float*)d_in[4];
    const float* b2 = (const float*)d_in[5];
    float* out = (float*)d_out;

    // workspace (~37 MB)
    int* gcur      = (int*)d_ws;                           // NB
    u32* pairs     = (u32*)(gcur + NB);                    // NB*CAP
    int* esrc_s    = (int*)(pairs + (size_t)NB * CAP);     // NB*CAP
    int* row_start = esrc_s + (size_t)NB * CAP;            // NN
    int* degs      = row_start + NN;                       // NN
    float* dinv    = (float*)(degs + NN);                  // NN
    u32* h1b       = (u32*)(dinv + NN);                    // NN*8
    u32* A1        = h1b + (size_t)NN * 8;                 // NN*8

    const int* esrc = ei;
    const int* edst = ei + NE;

    k_init          <<<(NB + 255) / 256, 256, 0, stream>>>(gcur);
    k_scatter_bucket<<<SGRID, 1024, 0, stream>>>(esrc, edst, gcur, pairs);
    k_sort_bucket   <<<NB, 1024, 0, stream>>>(pairs, gcur, esrc_s, row_start, degs, dinv);
    k_gemm1         <<<(NN + 63) / 64, 256, 0, stream>>>(x, W1, dinv, h1b);
    k_agg1          <<<(NN + 15) / 16, 1024, 0, stream>>>(row_start, degs, esrc_s, h1b, dinv, b1, A1);
    k_agg2_final    <<<(NN + 15) / 16, 1024, 0, stream>>>(row_start, degs, esrc_s, A1, dinv, W2, b2, out);
}

// Round 17
// 204.609 us; speedup vs baseline: 1.1665x; 1.1665x over previous
//
#include <hip/hip_runtime.h>
#include <math.h>

typedef unsigned int u32;

constexpr int NN = 100000;   // nodes
constexpr int NE = 3200000;  // edges
constexpr int DF = 512;      // in features
constexpr int NH = 16;       // hidden
constexpr int NC = 40;       // classes

constexpr int NB  = 512;     // buckets
constexpr int BSZ = 196;     // nodes per bucket (512*196 >= NN)
constexpr int CAP = 7168;    // per-bucket edge capacity (mean 6250, +11 sigma)
constexpr int SCHUNK = 8192;
constexpr int SGRID  = (NE + SCHUNK - 1) / SCHUNK;  // 391 blocks

// ---------------------------------------------------------------- bf16 helpers
__device__ __forceinline__ u32 pack_bf2(float lo, float hi) {
    u32 a = __float_as_uint(lo), b = __float_as_uint(hi);
    a += 0x7FFFu + ((a >> 16) & 1u);   // RNE
    b += 0x7FFFu + ((b >> 16) & 1u);
    return (a >> 16) | (b & 0xFFFF0000u);
}
__device__ __forceinline__ float bf_lo(u32 u) { return __uint_as_float(u << 16); }
__device__ __forceinline__ float bf_hi(u32 u) { return __uint_as_float(u & 0xFFFF0000u); }

// ---------------------------------------------------------------- init bucket cursors
__global__ void k_init(int* __restrict__ gcur) {
    int i = blockIdx.x * blockDim.x + threadIdx.x;
    if (i < NB) gcur[i] = i * CAP;
}

// ---------------------------------------------------------------- bucket counting-scatter
// Block-local counting sort by bucket, then COALESCED write-out (R15 proven).
__global__ __launch_bounds__(1024) void k_scatter_bucket(
    const int* __restrict__ src, const int* __restrict__ dst,
    int* __restrict__ gcur, u32* __restrict__ pairs) {
    __shared__ int hist[NB];
    __shared__ int lofs[NB];
    __shared__ int gpos[NB];
    __shared__ int lcur[NB];
    __shared__ u32 buf[SCHUNK];   // 32 KB
    const int t = threadIdx.x;
    for (int i = t; i < NB; i += 1024) { hist[i] = 0; lcur[i] = 0; }
    __syncthreads();

    const int base  = blockIdx.x * SCHUNK;
    const int total = min(SCHUNK, NE - base);
    int dr[SCHUNK / 1024], sr[SCHUNK / 1024];
    #pragma unroll
    for (int k = 0; k < SCHUNK / 1024; ++k) {
        const int i = base + k * 1024 + t;
        if (i < NE) {
            dr[k] = dst[i];
            sr[k] = src[i];
            atomicAdd(&hist[(unsigned)dr[k] / BSZ], 1);
        }
    }
    __syncthreads();
    if (t < NB) {
        lofs[t] = hist[t];
        if (hist[t]) gpos[t] = atomicAdd(&gcur[t], hist[t]);
    }
    __syncthreads();
    #pragma unroll
    for (int off = 1; off < NB; off <<= 1) {
        int v = 0;
        if (t < NB && t >= off) v = lofs[t - off];
        __syncthreads();
        if (t < NB) lofs[t] += v;
        __syncthreads();
    }
    if (t < NB) lofs[t] -= hist[t];   // exclusive
    __syncthreads();
    #pragma unroll
    for (int k = 0; k < SCHUNK / 1024; ++k) {
        const int i = base + k * 1024 + t;
        if (i < NE) {
            const unsigned d  = (unsigned)dr[k];
            const unsigned b  = d / BSZ;
            const unsigned dl = d - b * BSZ;
            const int off = atomicAdd(&lcur[b], 1);
            buf[lofs[b] + off] = (unsigned)sr[k] | (dl << 17);
        }
    }
    __syncthreads();
    for (int i = t; i < total; i += 1024) {
        int lo = 0, hi = NB - 1;
        #pragma unroll
        for (int s = 0; s < 9; ++s) {
            const int mid = (lo + hi + 1) >> 1;
            if (lofs[mid] <= i) lo = mid; else hi = mid - 1;
        }
        pairs[gpos[lo] + (i - lofs[lo])] = buf[i];
    }
}

// ---------------------------------------------------------------- per-bucket counting sort by dl
__global__ __launch_bounds__(1024) void k_sort_bucket(
    const u32* __restrict__ pairs, const int* __restrict__ gcur,
    int* __restrict__ esrc_s, int* __restrict__ row_start,
    int* __restrict__ degs, float* __restrict__ dinv) {
    __shared__ int hist[BSZ];
    __shared__ int scan[256];
    __shared__ int cur[BSZ];
    const int b = blockIdx.x, t = threadIdx.x;
    if (t < BSZ) hist[t] = 0;
    __syncthreads();

    const int base = b * CAP;
    const int end  = gcur[b];
    for (int p = base + t; p < end; p += 1024)
        atomicAdd(&hist[pairs[p] >> 17], 1);
    __syncthreads();

    const int h = (t < BSZ) ? hist[t] : 0;
    if (t < 256) scan[t] = (t < BSZ) ? h : 0;
    __syncthreads();
    #pragma unroll
    for (int off = 1; off < 256; off <<= 1) {
        int u = 0;
        if (t < 256 && t >= off) u = scan[t - off];
        __syncthreads();
        if (t < 256) scan[t] += u;
        __syncthreads();
    }
    if (t < BSZ) {
        const int st = scan[t] - h;   // exclusive
        cur[t] = st;
        const int n = b * BSZ + t;
        if (n < NN) {
            row_start[n] = base + st;
            degs[n] = h;
            dinv[n] = rsqrtf((float)(h + 1));
        }
    }
    __syncthreads();
    for (int p = base + t; p < end; p += 1024) {
        const u32 u = pairs[p];
        const int dl = u >> 17;
        const int pos = atomicAdd(&cur[dl], 1);
        esrc_s[base + pos] = (int)(u & 0x1FFFFu);
    }
}

// ---------------------------------------------------------------- layer-1 GEMM (R10 proven)
// x tile in LDS stride-68 (17 float4): b128 x-reads, conflict-free; W chunk
// in LDS broadcast b128; register-prefetch double buffer.
__global__ __launch_bounds__(256) void k_gemm1(
    const float* __restrict__ x, const float* __restrict__ W1,
    const float* __restrict__ dinv, u32* __restrict__ h1b) {
    __shared__ __align__(16) float sX[64 * 68];   // 17.4 KB
    __shared__ __align__(16) float sW[64 * 16];   // 4 KB
    const int t    = threadIdx.x;
    const int lane = t & 63;
    const int og   = t >> 6;

    const int row0 = blockIdx.x * 64;
    const int lr = t >> 2, cq = t & 3;
    const bool rv = (row0 + lr) < NN;
    const float* xrow = x + (size_t)(row0 + lr) * DF + cq * 16;

    float4 pf[4];
    #pragma unroll
    for (int j = 0; j < 4; ++j)
        pf[j] = rv ? *(const float4*)&xrow[4 * j] : make_float4(0.f, 0.f, 0.f, 0.f);
    float4 wpf = *(const float4*)&W1[t * 4];

    float a0 = 0.f, a1 = 0.f, a2 = 0.f, a3 = 0.f;

    for (int kc = 0; kc < DF; kc += 64) {
        #pragma unroll
        for (int j = 0; j < 4; ++j)
            *(float4*)&sX[lr * 68 + cq * 16 + 4 * j] = pf[j];
        *(float4*)&sW[t * 4] = wpf;
        __syncthreads();
        if (kc + 64 < DF) {
            #pragma unroll
            for (int j = 0; j < 4; ++j)
                pf[j] = rv ? *(const float4*)&xrow[kc + 64 + 4 * j]
                           : make_float4(0.f, 0.f, 0.f, 0.f);
            wpf = *(const float4*)&W1[(kc + 64) * NH + t * 4];
        }
        #pragma unroll
        for (int g = 0; g < 16; ++g) {
            const float4 xv4 = *(const float4*)&sX[lane * 68 + g * 4];
            const float xa[4] = {xv4.x, xv4.y, xv4.z, xv4.w};
            #pragma unroll
            for (int j = 0; j < 4; ++j) {
                const float4 wv = *(const float4*)&sW[(g * 4 + j) * NH + og * 4];
                a0 = fmaf(xa[j], wv.x, a0);
                a1 = fmaf(xa[j], wv.y, a1);
                a2 = fmaf(xa[j], wv.z, a2);
                a3 = fmaf(xa[j], wv.w, a3);
            }
        }
        __syncthreads();
    }
    const int gr = row0 + lane;
    if (gr < NN) {
        const float s = dinv[gr];
        const u32 w0 = pack_bf2(a0 * s, a1 * s);
        const u32 w1 = pack_bf2(a2 * s, a3 * s);
        *(uint2*)&h1b[(size_t)gr * 8 + og * 2] = make_uint2(w0, w1);
    }
}

// ---------------------------------------------------------------- CSR gather agg, layer 1
// wave per node: lane = l (u32 col 0..7) + 8*g (edge group 0..7)  [R15 proven]
__global__ __launch_bounds__(1024) void k_agg1(
    const int* __restrict__ row_start, const int* __restrict__ degs,
    const int* __restrict__ esrc_s, const u32* __restrict__ h1b,
    const float* __restrict__ dinv, const float* __restrict__ b1,
    u32* __restrict__ A1) {
    const int node = blockIdx.x * 16 + (threadIdx.x >> 6);
    if (node >= NN) return;
    const int lane = threadIdx.x & 63;
    const int l = lane & 7;
    const int g = lane >> 3;
    const int beg = row_start[node];
    const int end = beg + degs[node];

    float a0 = 0.f, a1 = 0.f;
    int e = beg + g;
    for (; e + 8 < end; e += 16) {
        const int s0 = esrc_s[e];
        const int s1 = esrc_s[e + 8];
        const u32 u0 = h1b[(size_t)s0 * 8 + l];
        const u32 u1 = h1b[(size_t)s1 * 8 + l];
        a0 += bf_lo(u0); a1 += bf_hi(u0);
        a0 += bf_lo(u1); a1 += bf_hi(u1);
    }
    if (e < end) {
        const u32 u0 = h1b[(size_t)esrc_s[e] * 8 + l];
        a0 += bf_lo(u0); a1 += bf_hi(u0);
    }
    a0 += __shfl_xor(a0, 8);  a1 += __shfl_xor(a1, 8);
    a0 += __shfl_xor(a0, 16); a1 += __shfl_xor(a1, 16);
    a0 += __shfl_xor(a0, 32); a1 += __shfl_xor(a1, 32);

    if (g == 0) {
        const float dn = dinv[node];
        const u32 su = h1b[(size_t)node * 8 + l];
        const float p0 = (a0 + bf_lo(su)) * dn + b1[2 * l];
        const float p1 = (a1 + bf_hi(su)) * dn + b1[2 * l + 1];
        A1[(size_t)node * 8 + l] = pack_bf2(fmaxf(p0, 0.f) * dn, fmaxf(p1, 0.f) * dn);
    }
}

// ---------------------------------------------------------------- CSR gather agg, layer 2 + W2 + log_softmax
__global__ __launch_bounds__(1024) void k_agg2_final(
    const int* __restrict__ row_start, const int* __restrict__ degs,
    const int* __restrict__ esrc_s, const u32* __restrict__ A1,
    const float* __restrict__ dinv, const float* __restrict__ W2,
    const float* __restrict__ b2, float* __restrict__ out) {
    __shared__ float sW2[NH * NC];
    __shared__ float sb2[NC];
    const int t = threadIdx.x;
    if (t < NH * NC) sW2[t] = W2[t];
    if (t >= 1024 - NC) sb2[t - (1024 - NC)] = b2[t - (1024 - NC)];
    __syncthreads();

    const int node = blockIdx.x * 16 + (t >> 6);
    if (node >= NN) return;
    const int lane = t & 63;
    const int l = lane & 7;
    const int g = lane >> 3;
    const int beg = row_start[node];
    const int end = beg + degs[node];

    float a0 = 0.f, a1 = 0.f;
    int e = beg + g;
    for (; e + 8 < end; e += 16) {
        const int s0 = esrc_s[e];
        const int s1 = esrc_s[e + 8];
        const u32 u0 = A1[(size_t)s0 * 8 + l];
        const u32 u1 = A1[(size_t)s1 * 8 + l];
        a0 += bf_lo(u0); a1 += bf_hi(u0);
        a0 += bf_lo(u1); a1 += bf_hi(u1);
    }
    if (e < end) {
        const u32 u0 = A1[(size_t)esrc_s[e] * 8 + l];
        a0 += bf_lo(u0); a1 += bf_hi(u0);
    }
    a0 += __shfl_xor(a0, 8);  a1 += __shfl_xor(a1, 8);
    a0 += __shfl_xor(a0, 16); a1 += __shfl_xor(a1, 16);
    a0 += __shfl_xor(a0, 32); a1 += __shfl_xor(a1, 32);

    const float dn = dinv[node];
    const u32 su = A1[(size_t)node * 8 + l];
    const float ag0 = (a0 + bf_lo(su)) * dn;   // channel 2l
    const float ag1 = (a1 + bf_hi(su)) * dn;   // channel 2l+1

    float z = (lane < NC) ? sb2[lane] : -1e30f;
    #pragma unroll
    for (int k = 0; k < 8; ++k) {
        const float v0 = __shfl(ag0, k);
        const float v1 = __shfl(ag1, k);
        if (lane < NC) {
            z = fmaf(v0, sW2[(2 * k) * NC + lane], z);
            z = fmaf(v1, sW2[(2 * k + 1) * NC + lane], z);
        }
    }
    float m = z;
    #pragma unroll
    for (int off = 1; off < 64; off <<= 1) m = fmaxf(m, __shfl_xor(m, off));
    float sum = (lane < NC) ? __expf(z - m) : 0.f;
    #pragma unroll
    for (int off = 1; off < 64; off <<= 1) sum += __shfl_xor(sum, off);
    const float lse = m + __logf(sum);
    if (lane < NC) out[(size_t)node * NC + lane] = z - lse;
}

// ---------------------------------------------------------------- launch
extern "C" void kernel_launch(void* const* d_in, const int* in_sizes, int n_in,
                              void* d_out, int out_size, void* d_ws, size_t ws_size,
                              hipStream_t stream) {
    const float* x  = (const float*)d_in[0];
    const int*   ei = (const int*)d_in[1];   // [2, NE] flat int32
    const float* W1 = (const float*)d_in[2];
    const float* b1 = (const float*)d_in[3];
    const float* W2 = (const float*)d_in[4];
    const float* b2 = (const float*)d_in[5];
    float* out = (float*)d_out;

    // workspace (~37 MB)
    int* gcur      = (int*)d_ws;                           // NB
    u32* pairs     = (u32*)(gcur + NB);                    // NB*CAP
    int* esrc_s    = (int*)(pairs + (size_t)NB * CAP);     // NB*CAP
    int* row_start = esrc_s + (size_t)NB * CAP;            // NN
    int* degs      = row_start + NN;                       // NN
    float* dinv    = (float*)(degs + NN);                  // NN
    u32* h1b       = (u32*)(dinv + NN);                    // NN*8
    u32* A1        = h1b + (size_t)NN * 8;                 // NN*8

    const int* esrc = ei;
    const int* edst = ei + NE;

    k_init          <<<(NB + 255) / 256, 256, 0, stream>>>(gcur);
    k_scatter_bucket<<<SGRID, 1024, 0, stream>>>(esrc, edst, gcur, pairs);
    k_sort_bucket   <<<NB, 1024, 0, stream>>>(pairs, gcur, esrc_s, row_start, degs, dinv);
    k_gemm1         <<<(NN + 63) / 64, 256, 0, stream>>>(x, W1, dinv, h1b);
    k_agg1          <<<(NN + 15) / 16, 1024, 0, stream>>>(row_start, degs, esrc_s, h1b, dinv, b1, A1);
    k_agg2_final    <<<(NN + 15) / 16, 1024, 0, stream>>>(row_start, degs, esrc_s, A1, dinv, W2, b2, out);
}